// Round 5
// baseline (319.045 us; speedup 1.0000x reference)
//
#include <hip/hip_runtime.h>
#include <math.h>

#define Bn 32
#define Ln 512
#define Dn 512
#define Hn 8
#define DHn 64
#define FFn 2048
#define Mn (Bn*Ln)   // 16384
#define QKVS 1536

typedef __attribute__((ext_vector_type(4))) float f32x4;
typedef __attribute__((ext_vector_type(8))) short short8;

__device__ __forceinline__ float bf2f(ushort u){ return __uint_as_float(((unsigned)u) << 16); }
__device__ __forceinline__ ushort f2bf(float f){
  unsigned u = __float_as_uint(f);
  u += 0x7FFFu + ((u >> 16) & 1u);
  return (ushort)(u >> 16);
}
// exact sigmoid-form of tanh-gelu: 0.5x(1+tanh(y)) == x*sigmoid(2y)
__device__ __forceinline__ float gelu_fast(float x){
  float y2 = 1.5957691216057308f * (x + 0.044715f*x*x*x);
  return x / (1.0f + __expf(-y2));
}

// async global->LDS, 16B per lane; LDS dest is wave-uniform base + lane*16
__device__ __forceinline__ void gload_lds16(const ushort* g, ushort* l){
  __builtin_amdgcn_global_load_lds(
      (__attribute__((address_space(1))) void*)(void*)g,
      (__attribute__((address_space(3))) void*)(void*)l, 16, 0, 0);
}

__device__ __forceinline__ void cvt4(const float* __restrict__ in, ushort* __restrict__ out, int u){
  float4 v = *(const float4*)(in + u*4);
  ushort4 o;
  o.x = f2bf(v.x); o.y = f2bf(v.y); o.z = f2bf(v.z); o.w = f2bf(v.w);
  *(ushort4*)(out + u*4) = o;
}

// ---------------- fused prep: 7 weight cvts + PE table + qkv bias pack ----------------
// unit = 4 elements. Wg|Wq|Wk|Wv|Wo (65536 u each) | W1|W2 (262144 u) | pe (65536 u) | bias (384 u)
__global__ __launch_bounds__(256) void prep_kernel(
    const float* __restrict__ Wg, const float* __restrict__ Wq, const float* __restrict__ Wk,
    const float* __restrict__ Wv, const float* __restrict__ Wo, const float* __restrict__ W1,
    const float* __restrict__ W2,
    const float* __restrict__ bq, const float* __restrict__ bk, const float* __restrict__ bv,
    ushort* __restrict__ wgb, ushort* __restrict__ wqkvb, ushort* __restrict__ wob,
    ushort* __restrict__ w1b, ushort* __restrict__ w2b,
    float* __restrict__ pe, float* __restrict__ bqkv)
{
  int u = blockIdx.x*256 + threadIdx.x;
  const int WU = 65536, FU = 262144;
  if (u < WU){ cvt4(Wg, wgb, u); return; }            u -= WU;
  if (u < WU){ cvt4(Wq, wqkvb, u); return; }          u -= WU;
  if (u < WU){ cvt4(Wk, wqkvb + 262144, u); return; } u -= WU;
  if (u < WU){ cvt4(Wv, wqkvb + 524288, u); return; } u -= WU;
  if (u < WU){ cvt4(Wo, wob, u); return; }            u -= WU;
  if (u < FU){ cvt4(W1, w1b, u); return; }            u -= FU;
  if (u < FU){ cvt4(W2, w2b, u); return; }            u -= FU;
  if (u < WU){                                        // PE table
    int e = u*4; int l = e >> 9; int d0 = e & 511;
    #pragma unroll
    for (int p=0;p<2;p++){
      int i = (d0 >> 1) + p;
      float dv = expf((float)(2*i) * (-9.210340371976184f/512.0f));
      float ang = (float)l * dv;
      pe[e + 2*p]     = sinf(ang);
      pe[e + 2*p + 1] = cosf(ang);
    }
    return;
  }
  u -= WU;
  if (u < 384){
    int e = u*4;
    #pragma unroll
    for (int j=0;j<4;j++){
      int i = e + j;
      bqkv[i] = (i < 512) ? bq[i] : (i < 1024) ? bk[i-512] : bv[i-1024];
    }
  }
}

// ---------------- f32 -> bf16 convert (x only) ----------------
__global__ void cvt_kernel(const float* __restrict__ in, ushort* __restrict__ out, int n){
  int i = (blockIdx.x*256 + threadIdx.x)*4;
  if (i >= n) return;
  cvt4(in, out, i >> 2);
}

// ---------------- GEMM: C[M x N] = A[M x K](bf16) @ W[N x K]^T, f32 acc ----------------
// BM=BN=128, BK=64, dbuf LDS (64KB), 4 waves (2x2), wave tile 64x64, 32 MFMA/K-step.
// Pipeline (T3-minimum): stage(next) -> compute(cur) -> ONE __syncthreads per K-step
// (syncthreads emits vmcnt(0)+lgkmcnt(0)+barrier: loads fly under the MFMAs).
// Both-sides XOR swizzle: linear gload_lds dest, source col u_log=(l&7)^(l>>3), read col ^(row&7).
// Grid: 1D, XCD-bijective remap (m157), col-fastest decode.
// MODE: 0 gate  1 qkv (q-scale; V written TRANSPOSED to outb2[(b*H+h)*64+dh][key])
//       2 bias+res->f32  3 gelu->bf16  4 gelu+res->f32
template<int MODE>
__global__ __launch_bounds__(256) void gemm_kernel(
    const ushort* __restrict__ A, const ushort* __restrict__ W,
    const float* __restrict__ bias,
    const float* __restrict__ res,
    const float* __restrict__ spk, const float* __restrict__ pe,
    float* __restrict__ outf, ushort* __restrict__ outb, ushort* __restrict__ outb2,
    int K, int N, int gx)
{
  __shared__ ushort lA[2][128][64];
  __shared__ ushort lW[2][128][64];
  int t = threadIdx.x;
  int wave = t >> 6, lane = t & 63;
  int wr = wave >> 1, wc = wave & 1;
  int g = lane >> 4, r16 = lane & 15;

  int nwg = gx * (Mn/128);
  int wg = blockIdx.x;
  int tile = (wg & 7)*(nwg >> 3) + (wg >> 3);
  int trow = tile / gx;
  int tcol = tile - trow*gx;
  int rowBase = trow * 128;
  int colBase = tcol * 128;

  int srow8 = lane >> 3;
  int sucol = ((lane & 7) ^ srow8) * 8;
  const ushort* gA = A + (size_t)(rowBase + wave*8 + srow8)*K + sucol;
  const ushort* gW = W + (size_t)(colBase + wave*8 + srow8)*K + sucol;

  f32x4 acc[4][4];
  #pragma unroll
  for (int m=0;m<4;m++)
    #pragma unroll
    for (int n=0;n<4;n++) acc[m][n] = (f32x4)0.0f;

  // prologue stage into buf 0
  {
    ushort* la = &lA[0][0][0] + wave*512;
    ushort* lw = &lW[0][0][0] + wave*512;
    #pragma unroll
    for (int c=0;c<4;c++){
      gload_lds16(gA + (size_t)c*32*K, la + c*2048);
      gload_lds16(gW + (size_t)c*32*K, lw + c*2048);
    }
  }
  __syncthreads();

  int cb = 0;
  for (int k0 = 0; k0 < K; k0 += 64){
    if (k0 + 64 < K){
      ushort* la = &lA[cb^1][0][0] + wave*512;
      ushort* lw = &lW[cb^1][0][0] + wave*512;
      #pragma unroll
      for (int c=0;c<4;c++){
        gload_lds16(gA + (size_t)c*32*K + k0 + 64, la + c*2048);
        gload_lds16(gW + (size_t)c*32*K + k0 + 64, lw + c*2048);
      }
    }
    #pragma unroll
    for (int ks=0; ks<2; ks++){
      short8 af[4], bfr[4];
      #pragma unroll
      for (int m=0;m<4;m++){
        int row = wr*64 + m*16 + r16;
        af[m] = *(const short8*)&lA[cb][row][(((ks<<2)+g) ^ (r16 & 7))*8];
      }
      #pragma unroll
      for (int n=0;n<4;n++){
        int row = wc*64 + n*16 + r16;
        bfr[n] = *(const short8*)&lW[cb][row][(((ks<<2)+g) ^ (r16 & 7))*8];
      }
      #pragma unroll
      for (int m=0;m<4;m++)
        #pragma unroll
        for (int n=0;n<4;n++)
          acc[m][n] = __builtin_amdgcn_mfma_f32_16x16x32_bf16(af[m], bfr[n], acc[m][n], 0, 0, 0);
    }
    __syncthreads();   // drains next-tile loads (post-compute) + joins cur readers
    cb ^= 1;
  }

  #pragma unroll
  for (int m=0;m<4;m++){
    #pragma unroll
    for (int n=0;n<4;n++){
      int gc = colBase + wc*64 + n*16 + r16;
      if constexpr (MODE == 1){
        if (gc < 1024){   // block-uniform branch (colBase multiple of 128)
          float sc = (gc < 512) ? 0.125f : 1.0f;
          #pragma unroll
          for (int j=0;j<4;j++){
            int gr = rowBase + wr*64 + m*16 + g*4 + j;
            outb[(size_t)gr*N + gc] = f2bf((acc[m][n][j] + bias[gc]) * sc);
          }
        } else {          // V -> transposed [(b*H+h)*64+dh][key], 8B stores
          int dhg = gc - 1024;
          int gr0 = rowBase + wr*64 + m*16 + g*4;
          int bb = gr0 >> 9, l0 = gr0 & 511;
          ushort4 o4;
          o4.x = f2bf(acc[m][n][0] + bias[gc]);
          o4.y = f2bf(acc[m][n][1] + bias[gc]);
          o4.z = f2bf(acc[m][n][2] + bias[gc]);
          o4.w = f2bf(acc[m][n][3] + bias[gc]);
          *(ushort4*)(outb2 + ((size_t)(bb*Hn + (dhg>>6))*DHn + (dhg & 63))*Ln + l0) = o4;
        }
      } else {
        #pragma unroll
        for (int j=0;j<4;j++){
          int gr = rowBase + wr*64 + m*16 + g*4 + j;
          size_t o = (size_t)gr * N + gc;
          float c = acc[m][n][j];
          if constexpr (MODE == 0){
            float s = 1.0f/(1.0f + __expf(-c));
            float rv = s * res[o] + spk[o] + pe[(gr & (Ln-1))*Dn + gc];
            outf[o] = rv; outb[o] = f2bf(rv);
          } else if constexpr (MODE == 2){
            outf[o] = c + bias[gc] + res[o];
          } else if constexpr (MODE == 3){
            outb[o] = f2bf(gelu_fast(c + bias[gc]));
          } else {
            outf[o] = gelu_fast(c + bias[gc]) + res[o];
          }
        }
      }
    }
  }
}

// ---------------- MFMA flash attention ----------------
// grid (L/128, H, B), 256 thr = 4 waves; wave w owns 32 q-rows.
// K tile double-buffered in LDS (global loads issued BEFORE QK^T, written after PV).
// V read directly from pre-transposed vtb[(b*H+h)*64+dh][key] (L2-hot, 64KB/(b,h)).
// P staged through wave-private LDS.
__global__ __launch_bounds__(256) void attn_mfma_kernel(
    const ushort* __restrict__ qb, const ushort* __restrict__ kb, const ushort* __restrict__ vtb,
    const int* __restrict__ mask, ushort* __restrict__ ctxb)
{
  __shared__ ushort lK[2][64][72];
  __shared__ ushort lP[4][32][72];

  int t = threadIdx.x;
  int w = t >> 6, lane = t & 63;
  int g = lane >> 4, r16 = lane & 15;
  int b = blockIdx.z, h = blockIdx.y;
  int qbase = blockIdx.x*128 + w*32;

  // K staging coords: thread handles keys (t>>3) and (t>>3)+32, 8-col chunk (t&7)*8
  int key0 = t >> 3, key1 = key0 + 32;
  int c8s = (t & 7) * 8;
  const ushort* kbase = kb + (size_t)(b*Ln)*QKVS + h*DHn + c8s;
  const ushort* vt = vtb + (size_t)((b*Hn + h)*DHn) * Ln;

  short8 af_q[2][2];
  #pragma unroll
  for (int m=0;m<2;m++)
    #pragma unroll
    for (int ks=0;ks<2;ks++)
      af_q[m][ks] = *(const short8*)(qb + (size_t)(b*Ln + qbase + m*16 + r16)*QKVS + h*DHn + ks*32 + g*8);

  f32x4 acc_ctx[2][4];
  #pragma unroll
  for (int m=0;m<2;m++)
    #pragma unroll
    for (int n=0;n<4;n++) acc_ctx[m][n] = (f32x4)0.0f;
  float mrun[2][4], lrun[2][4];
  #pragma unroll
  for (int m=0;m<2;m++)
    #pragma unroll
    for (int j=0;j<4;j++){ mrun[m][j] = -INFINITY; lrun[m][j] = 0.0f; }

  // prologue: stage K tile 0
  {
    short8 ka = *(const short8*)(kbase + (size_t)key0*QKVS);
    short8 kc = *(const short8*)(kbase + (size_t)key1*QKVS);
    *(short8*)&lK[0][key0][c8s] = ka;
    *(short8*)&lK[0][key1][c8s] = kc;
  }
  __syncthreads();
  int cb = 0;

  for (int kb0 = 0; kb0 < Ln; kb0 += 64){
    short8 kna, knb;
    bool more = (kb0 + 64 < Ln);
    if (more){   // issue next K-tile loads early (latency hides under QK+softmax)
      kna = *(const short8*)(kbase + (size_t)(kb0 + 64 + key0)*QKVS);
      knb = *(const short8*)(kbase + (size_t)(kb0 + 64 + key1)*QKVS);
    }

    // S = Q @ K^T
    f32x4 acc_s[2][4];
    #pragma unroll
    for (int m=0;m<2;m++)
      #pragma unroll
      for (int n=0;n<4;n++) acc_s[m][n] = (f32x4)0.0f;
    __builtin_amdgcn_s_setprio(1);
    #pragma unroll
    for (int ks=0;ks<2;ks++){
      short8 bf_k[4];
      #pragma unroll
      for (int n=0;n<4;n++)
        bf_k[n] = *(const short8*)&lK[cb][n*16 + r16][ks*32 + g*8];
      #pragma unroll
      for (int m=0;m<2;m++)
        #pragma unroll
        for (int n=0;n<4;n++)
          acc_s[m][n] = __builtin_amdgcn_mfma_f32_16x16x32_bf16(af_q[m][ks], bf_k[n], acc_s[m][n], 0, 0, 0);
    }
    __builtin_amdgcn_s_setprio(0);

    // mask keys
    #pragma unroll
    for (int n=0;n<4;n++){
      if (mask[b*Ln + kb0 + n*16 + r16] == 0){
        #pragma unroll
        for (int m=0;m<2;m++)
          #pragma unroll
          for (int j=0;j<4;j++) acc_s[m][n][j] = -1e10f;
      }
    }

    // online softmax; P -> bf16 in wave-private LDS
    #pragma unroll
    for (int m=0;m<2;m++){
      #pragma unroll
      for (int j=0;j<4;j++){
        float tmax = fmaxf(fmaxf(acc_s[m][0][j], acc_s[m][1][j]),
                           fmaxf(acc_s[m][2][j], acc_s[m][3][j]));
        #pragma unroll
        for (int off=1; off<16; off<<=1) tmax = fmaxf(tmax, __shfl_xor(tmax, off));
        float newm = fmaxf(mrun[m][j], tmax);
        float alpha = __expf(mrun[m][j] - newm);
        float p0 = __expf(acc_s[m][0][j] - newm);
        float p1 = __expf(acc_s[m][1][j] - newm);
        float p2 = __expf(acc_s[m][2][j] - newm);
        float p3 = __expf(acc_s[m][3][j] - newm);
        float tsum = (p0+p1)+(p2+p3);
        #pragma unroll
        for (int off=1; off<16; off<<=1) tsum += __shfl_xor(tsum, off);
        lrun[m][j] = lrun[m][j]*alpha + tsum;
        mrun[m][j] = newm;
        #pragma unroll
        for (int n2=0;n2<4;n2++) acc_ctx[m][n2][j] *= alpha;
        int prow = m*16 + g*4 + j;
        lP[w][prow][0*16 + r16] = f2bf(p0);
        lP[w][prow][1*16 + r16] = f2bf(p1);
        lP[w][prow][2*16 + r16] = f2bf(p2);
        lP[w][prow][3*16 + r16] = f2bf(p3);
      }
    }

    // ctx += P @ V  (A from wave-private lP; B direct from global V^T, L2-hot)
    __builtin_amdgcn_s_setprio(1);
    #pragma unroll
    for (int ks2=0;ks2<2;ks2++){
      short8 af_p[2], bf_v[4];
      #pragma unroll
      for (int m=0;m<2;m++)
        af_p[m] = *(const short8*)&lP[w][m*16 + r16][ks2*32 + g*8];
      #pragma unroll
      for (int n=0;n<4;n++)
        bf_v[n] = *(const short8*)(vt + (size_t)(n*16 + r16)*Ln + kb0 + ks2*32 + g*8);
      #pragma unroll
      for (int m=0;m<2;m++)
        #pragma unroll
        for (int n=0;n<4;n++)
          acc_ctx[m][n] = __builtin_amdgcn_mfma_f32_16x16x32_bf16(af_p[m], bf_v[n], acc_ctx[m][n], 0, 0, 0);
    }
    __builtin_amdgcn_s_setprio(0);

    if (more){
      *(short8*)&lK[cb^1][key0][c8s] = kna;
      *(short8*)&lK[cb^1][key1][c8s] = knb;
    }
    __syncthreads();
    cb ^= 1;
  }

  #pragma unroll
  for (int m=0;m<2;m++){
    #pragma unroll
    for (int j=0;j<4;j++){
      float inv = 1.0f / lrun[m][j];
      int gr = qbase + m*16 + g*4 + j;
      #pragma unroll
      for (int n=0;n<4;n++){
        ctxb[(size_t)(b*Ln + gr)*Dn + h*DHn + n*16 + r16] = f2bf(acc_ctx[m][n][j] * inv);
      }
    }
  }
}

// ---------------- layernorm: one wave per row (D=512), out bf16 ----------------
__global__ __launch_bounds__(256) void ln_kernel(
    const float* __restrict__ hbuf, const float* __restrict__ gamma, const float* __restrict__ beta,
    ushort* __restrict__ out)
{
  int row = blockIdx.x*4 + (threadIdx.x >> 6);
  int lane = threadIdx.x & 63;
  const float* p = hbuf + (size_t)row*Dn + lane*8;
  float4 a = *(const float4*)p;
  float4 c = *(const float4*)(p + 4);
  float v[8] = {a.x,a.y,a.z,a.w,c.x,c.y,c.z,c.w};
  float s = 0.f, ss = 0.f;
  #pragma unroll
  for (int j=0;j<8;j++){ s += v[j]; ss += v[j]*v[j]; }
  #pragma unroll
  for (int off=32; off>0; off>>=1){ s += __shfl_xor(s, off); ss += __shfl_xor(ss, off); }
  float mu = s * (1.0f/Dn);
  float var = ss * (1.0f/Dn) - mu*mu;
  float rstd = rsqrtf(var + 1e-5f);
  ushort o8[8];
  #pragma unroll
  for (int j=0;j<8;j++) o8[j] = f2bf((v[j]-mu)*rstd*gamma[lane*8+j] + beta[lane*8+j]);
  ushort* op = out + (size_t)row*Dn + lane*8;
  *(ushort4*)op       = make_ushort4(o8[0],o8[1],o8[2],o8[3]);
  *(ushort4*)(op + 4) = make_ushort4(o8[4],o8[5],o8[6],o8[7]);
}

extern "C" void kernel_launch(void* const* d_in, const int* in_sizes, int n_in,
                              void* d_out, int out_size, void* d_ws, size_t ws_size,
                              hipStream_t stream) {
  (void)in_sizes; (void)n_in; (void)out_size; (void)ws_size;
  const float* x    = (const float*)d_in[0];
  const int*   mask = (const int*)d_in[1];
  const float* spk  = (const float*)d_in[2];
  const float* Wg   = (const float*)d_in[3];
  const float* Wq   = (const float*)d_in[4];  const float* bq = (const float*)d_in[5];
  const float* Wk   = (const float*)d_in[6];  const float* bk = (const float*)d_in[7];
  const float* Wv   = (const float*)d_in[8];  const float* bv = (const float*)d_in[9];
  const float* Wo   = (const float*)d_in[10]; const float* bo = (const float*)d_in[11];
  const float* lng  = (const float*)d_in[12]; const float* lnbeta = (const float*)d_in[13];
  const float* W1   = (const float*)d_in[14]; const float* b1 = (const float*)d_in[15];
  const float* W2   = (const float*)d_in[16]; const float* b2 = (const float*)d_in[17];
  float* out = (float*)d_out;

  char* w = (char*)d_ws;
  size_t o = 0;
  ushort* xbf   = (ushort*)(w + o); o += (size_t)Mn*Dn*2;    // dead after gate   } overlapped
  ushort* xinb  = (ushort*)(w + o); o += (size_t)Mn*Dn*2;    // dead after qkv    } by midb
  ushort* qkvb  = (ushort*)(w + o); o += (size_t)Mn*QKVS*2;  // dead after attn   } (67.1MB need)
  ushort* vtb   = (ushort*)(w + o); o += (size_t)Mn*Dn*2;    // V transposed [(b,h,dh)][key]
  ushort* ctxb  = (ushort*)(w + o); o += (size_t)Mn*Dn*2;
  float*  xinf  = (float*)(w + o);  o += (size_t)Mn*Dn*4;
  float*  hbuf  = (float*)(w + o);  o += (size_t)Mn*Dn*4;
  ushort* lnbuf = (ushort*)(w + o); o += (size_t)Mn*Dn*2;
  ushort* wgb   = (ushort*)(w + o); o += (size_t)Dn*Dn*2;
  ushort* wqkvb = (ushort*)(w + o); o += (size_t)QKVS*Dn*2;
  ushort* wob   = (ushort*)(w + o); o += (size_t)Dn*Dn*2;
  ushort* w1b   = (ushort*)(w + o); o += (size_t)FFn*Dn*2;
  ushort* w2b   = (ushort*)(w + o); o += (size_t)Dn*FFn*2;
  float*  pebuf = (float*)(w + o);  o += (size_t)Ln*Dn*4;
  float*  bqkv  = (float*)(w + o);  o += (size_t)QKVS*4;
  ushort* midb  = xbf;  // M x FF bf16 (67MB), overlaps xbf+xinb+qkvb (all dead by ff1)

  // fused prep: all weight cvts + PE + bias pack (one launch)
  hipLaunchKernelGGL(prep_kernel, dim3(3586), dim3(256), 0, stream,
                     Wg, Wq, Wk, Wv, Wo, W1, W2, bq, bk, bv,
                     wgb, wqkvb, wob, w1b, w2b, pebuf, bqkv);
  hipLaunchKernelGGL(cvt_kernel, dim3((Mn*Dn/4)/256), dim3(256), 0, stream, x, xbf, Mn*Dn);

  // gate: xin = sigmoid(x@Wg^T)*x + spk + pe  -> xinf (f32) + xinb (bf16)
  hipLaunchKernelGGL((gemm_kernel<0>), dim3((Dn/128)*(Mn/128)), dim3(256), 0, stream,
                     xbf, wgb, (const float*)nullptr, x, spk, pebuf, xinf, xinb, (ushort*)nullptr,
                     Dn, Dn, Dn/128);
  // fused qkv: q,k -> qkvb[M][1536]; v -> vtb transposed
  hipLaunchKernelGGL((gemm_kernel<1>), dim3((QKVS/128)*(Mn/128)), dim3(256), 0, stream,
                     xinb, wqkvb, bqkv, (const float*)nullptr, (const float*)nullptr, (const float*)nullptr,
                     (float*)nullptr, qkvb, vtb, Dn, QKVS, QKVS/128);
  // attention (MFMA flash, V^T direct from L2)
  hipLaunchKernelGGL(attn_mfma_kernel, dim3(Ln/128, Hn, Bn), dim3(256), 0, stream,
                     qkvb, qkvb + 512, vtb, mask, ctxb);
  // h = ctx@Wo^T + bo + xin
  hipLaunchKernelGGL((gemm_kernel<2>), dim3((Dn/128)*(Mn/128)), dim3(256), 0, stream,
                     ctxb, wob, bo, xinf, (const float*)nullptr, (const float*)nullptr,
                     hbuf, (ushort*)nullptr, (ushort*)nullptr, Dn, Dn, Dn/128);
  // layernorm
  hipLaunchKernelGGL(ln_kernel, dim3(Mn/4), dim3(256), 0, stream, hbuf, lng, lnbeta, lnbuf);
  // mid = gelu(ln@W1^T + b1)
  hipLaunchKernelGGL((gemm_kernel<3>), dim3((FFn/128)*(Mn/128)), dim3(256), 0, stream,
                     lnbuf, w1b, b1, (const float*)nullptr, (const float*)nullptr, (const float*)nullptr,
                     (float*)nullptr, midb, (ushort*)nullptr, Dn, FFn, FFn/128);
  // out = gelu(mid@W2^T + b2) + h
  hipLaunchKernelGGL((gemm_kernel<4>), dim3((Dn/128)*(Mn/128)), dim3(256), 0, stream,
                     midb, w2b, b2, hbuf, (const float*)nullptr, (const float*)nullptr,
                     out, (ushort*)nullptr, (ushort*)nullptr, FFn, Dn, Dn/128);
}